// Round 11
// baseline (24791.753 us; speedup 1.0000x reference)
//
#include <hip/hip_runtime.h>

typedef _Float16 f16;
typedef _Float16 f16x8 __attribute__((ext_vector_type(8)));
typedef float f32x4 __attribute__((ext_vector_type(4)));
typedef unsigned int u32;
typedef u32 u32x4 __attribute__((ext_vector_type(4)));
typedef u32 u32x2 __attribute__((ext_vector_type(2)));

#define BS 64
#define SL 256
#define FL 256
#define SI 512
#define SH 512
#define NBLK 256
#define SLAB 6144   // units (16B) per tagged h slab: 64 rows x 32 nt x 3 u

__device__ __forceinline__ float sigmoidf_(float x) { return 1.f / (1.f + __expf(-x)); }
__device__ __forceinline__ float tanhf_(float x) { float e = __expf(2.f * x); return 1.f - 2.f / (e + 1.f); }

__device__ __forceinline__ f16x8 ldg_cohere(const f16* p) {
  f16x8 r;
  asm volatile("global_load_dwordx4 %0, %1, off sc0 sc1" : "=v"(r) : "v"(p) : "memory");
  return r;
}
__device__ __forceinline__ u32x4 ldg_tag(const u32x4* p) {
  u32x4 r;
  asm volatile("global_load_dwordx4 %0, %1, off sc0 sc1" : "=v"(r) : "v"(p) : "memory");
  return r;
}
__device__ __forceinline__ void stg_tag(u32x4* p, u32x4 v) {
  asm volatile("global_store_dwordx4 %0, %1, off sc0 sc1" :: "v"(p), "v"(v) : "memory");
}

// Weights packed in MFMA-fragment order (unchanged):
// n = g*512 + nt*16 + (lane&15), k = kh*512 + kk*32 + (lane>>4)*8 + j
__global__ void conv_w(const float* __restrict__ W, const float* __restrict__ V,
                       f16* __restrict__ out) {
  long idx = (long)blockIdx.x * blockDim.x + threadIdx.x;  // total 2^25
  int j    = (int)(idx & 7);
  int lane = (int)((idx >> 3) & 63);
  int kk   = (int)((idx >> 9) & 15);
  int kh   = (int)((idx >> 13) & 1);
  int g    = (int)((idx >> 14) & 3);
  int nt   = (int)((idx >> 16) & 31);
  long cell = idx >> 21;
  int n = g * 512 + nt * 16 + (lane & 15);
  int k = kh * 512 + kk * 32 + (lane >> 4) * 8 + j;
  float v = (k < 512) ? W[(cell * 512 + k) * 2048 + n]
                      : V[(cell * 512 + (k - 512)) * 2048 + n];
  out[idx] = (f16)v;
}

__global__ void conv_x(const float* __restrict__ x, f16* __restrict__ xt) {
  long idx = (long)blockIdx.x * blockDim.x + threadIdx.x;  // 256*64*512
  int i = (int)(idx & 511);
  int b = (int)((idx >> 9) & 63);
  int t = (int)(idx >> 15);
  xt[idx] = (f16)x[((long)b * SL + t) * SI + i];
}

__global__ void conv_fin(const float* __restrict__ finW, f16* __restrict__ fint) {
  long idx = (long)blockIdx.x * blockDim.x + threadIdx.x;  // 512*512
  int k = (int)(idx & 511);
  int n = (int)(idx >> 9);
  fint[idx] = (f16)finW[(long)k * SI + n];
}

// h_enc both parities = enc_h0 (encoder keeps dense format)
__global__ void init_state(const float* __restrict__ h0e, f16* __restrict__ h_enc) {
  long idx = (long)blockIdx.x * blockDim.x + threadIdx.x;  // 131072
  f16 he = (f16)h0e[idx];
  h_enc[idx] = he;
  h_enc[idx + 131072] = he;
}

// dec_h0 -> tagged units in par=1 slabs, tag = 4+E (acts as step T(v=-1,E))
__global__ void init_dec_tags(const float* __restrict__ h0d, u32x4* __restrict__ hdt) {
  int i = blockIdx.x * blockDim.x + threadIdx.x;  // 4*64*96 = 24576
  int E = i / 6144;
  int r = i - E * 6144;
  int row = r / 96;
  int rem = r - row * 96;
  int unt = rem / 3;
  int u = rem - unt * 3;
  int c0 = unt * 16 + u * 6;
  const float* src = h0d + (long)E * 32768 + row * 512 + c0;
  u32 d[3] = {0, 0, 0};
  int count = (u == 2) ? 4 : 6;
  for (int k = 0; k < count; k += 2) {
    f16 a = (f16)src[k], b = (f16)src[k + 1];
    d[k >> 1] = (u32)__builtin_bit_cast(unsigned short, a) |
                ((u32)__builtin_bit_cast(unsigned short, b) << 16);
  }
  u32x4 val = {d[0], d[1], d[2], (u32)(4 + E)};
  hdt[(4 + E) * SLAB + r] = val;
}

__device__ __forceinline__ void store_h_agent(f16* p, float v) {
  f16 h = (f16)v;
  __hip_atomic_store((unsigned short*)p, __builtin_bit_cast(unsigned short, h),
                     __ATOMIC_RELAXED, __HIP_MEMORY_SCOPE_AGENT);
}

#define SWZ(ROW, BOFF) (((ROW) << 10) + ((BOFF) ^ ((((ROW) & 7)) << 4)))

#define VMCNT0() do {                                                             \
    asm volatile("s_waitcnt vmcnt(0)" ::: "memory");                              \
    __builtin_amdgcn_sched_barrier(0);                                            \
  } while (0)

#define RAWBAR() do {                                                             \
    asm volatile("s_waitcnt lgkmcnt(0)" ::: "memory");                            \
    __builtin_amdgcn_sched_barrier(0);                                            \
    __builtin_amdgcn_s_barrier();                                                 \
    __builtin_amdgcn_sched_barrier(0);                                            \
  } while (0)

#define WAVE_ORDER() do {                                                          \
    asm volatile("s_waitcnt vmcnt(16)" ::: "memory");                              \
    __builtin_amdgcn_sched_barrier(0);                                             \
  } while (0)

// Encoder group barrier (128 blocks sharing emt) — unchanged from R10.
#define END_STEP_ENC(TARGET) do {                                                  \
    __builtin_amdgcn_s_barrier();                                                  \
    asm volatile("" ::: "memory");                                                 \
    if (tid == 0)                                                                  \
      __hip_atomic_store(&bar[bflag], (TARGET), __ATOMIC_RELAXED,                  \
                         __HIP_MEMORY_SCOPE_AGENT);                                \
    if (wid == 0) {                                                                \
      for (;;) {                                                                   \
        int a0 = __hip_atomic_load(&bar[pe0], __ATOMIC_RELAXED,                    \
                                   __HIP_MEMORY_SCOPE_AGENT);                      \
        int a1 = __hip_atomic_load(&bar[pe1], __ATOMIC_RELAXED,                    \
                                   __HIP_MEMORY_SCOPE_AGENT);                      \
        if (a0 >= (TARGET) && a1 >= (TARGET)) break;                               \
        __builtin_amdgcn_s_sleep(1);                                               \
      }                                                                            \
    }                                                                              \
    __builtin_amdgcn_s_barrier();                                                  \
    asm volatile("" ::: "memory");                                                 \
    __builtin_amdgcn_sched_barrier(0);                                             \
  } while (0)

// Encoder body (R10 structure) + one-time tagged state0 emission at v==1023.
#define ENC_BODY(DD, P, TARGET) do {                                               \
    const int v = (DD) - eslot;                                                    \
    if (v >= 0 && v < 1024) {                                                      \
      const int L = v & 3, t = v >> 2;                                             \
      const f16* inp = (eslot == 0) ? (xt + (long)t * HSz)                         \
                                    : (h_enc + ((P)*4 + (eslot - 1)) * HSz);       \
      const f16* hin = h_enc + ((P)*4 + eslot) * HSz;                              \
      f16* hout = h_enc + ((1 - (P))*4 + eslot) * HSz;                             \
      {                                                                            \
        const f16* c0p = inp + emt * 16384;                                        \
        const f16* c1p = hin + emt * 16384;                                        \
        f16x8 tr[8];                                                               \
        _Pragma("unroll")                                                          \
        for (int k2 = 0; k2 < 4; ++k2) {                                           \
          const int s2 = tid + k2 * 512, row = s2 >> 6, c16 = s2 & 63;             \
          tr[k2]     = ldg_cohere(c0p + row * 512 + c16 * 8);                      \
          tr[k2 + 4] = ldg_cohere(c1p + row * 512 + c16 * 8);                      \
        }                                                                          \
        VMCNT0();                                                                  \
        _Pragma("unroll")                                                          \
        for (int k2 = 0; k2 < 4; ++k2) {                                           \
          const int s2 = tid + k2 * 512, row = s2 >> 6, c16 = s2 & 63;             \
          *(f16x8*)(AsBuf + SWZ(row, c16 * 16)) = tr[k2];                          \
          *(f16x8*)(AsBuf + 32768 + SWZ(row, c16 * 16)) = tr[k2 + 4];              \
        }                                                                          \
      }                                                                            \
      RAWBAR();                                                                    \
      f32x4 acc0 = 0.f, acc1 = 0.f;                                                \
      _Pragma("unroll")                                                            \
      for (int kk = 0; kk < 16; ++kk) {                                            \
        f16x8 a0 = *(const f16x8*)(AsBuf + kh * 32768 +                            \
                                   SWZ(col, kk * 64 + kg * 16));                   \
        f16x8 a1 = *(const f16x8*)(AsBuf + kh * 32768 +                            \
                                   SWZ(col + 16, kk * 64 + kg * 16));              \
        acc0 = __builtin_amdgcn_mfma_f32_16x16x32_f16(a0, B[kk], acc0, 0,0,0);     \
        acc1 = __builtin_amdgcn_mfma_f32_16x16x32_f16(a1, B[kk], acc1, 0,0,0);     \
      }                                                                            \
      _Pragma("unroll")                                                            \
      for (int r = 0; r < 4; ++r) {                                                \
        zredE[wid][kg*4 + r][col] = acc0[r];                                       \
        zredE[wid][16 + kg*4 + r][col] = acc1[r];                                  \
      }                                                                            \
      RAWBAR();                                                                    \
      const bool s0f = (v == 1023) && (eslot == 3);                                \
      {                                                                            \
        const int row = tid >> 4, ci = tid & 15, n = n0 + ci;                      \
        const float* bl = bias_enc_lds + L * 64 + ci;                              \
        float zf = bl[0]  + zredE[0][row][ci] + zredE[4][row][ci];                 \
        float zi = bl[16] + zredE[1][row][ci] + zredE[5][row][ci];                 \
        float zg = bl[32] + zredE[2][row][ci] + zredE[6][row][ci];                 \
        float zo = bl[48] + zredE[3][row][ci] + zredE[7][row][ci];                 \
        float f_ = sigmoidf_(zf), i_ = sigmoidf_(zi);                              \
        float g_ = tanhf_(zg),   o_ = sigmoidf_(zo);                               \
        const int grow = emt * 32 + row;                                           \
        float cin = (v == 0) ? enc_c0[(long)eslot * HSz + grow * SH + n] : ce;     \
        float cc = f_ * cin + i_ * g_;                                             \
        ce = cc;                                                                   \
        float hv = o_ * tanhf_(cc);                                                \
        store_h_agent(hout + grow * SH + n, hv);                                   \
        if (s0f) pb16[row * 16 + ci] = (f16)hv;                                    \
      }                                                                            \
      if (s0f) {                                                                   \
        RAWBAR();                                                                  \
        if (tid < 96) {                                                            \
          int u = tid % 3, rowp = tid / 3;                                         \
          const char* pbc = (const char*)pb16 + rowp * 32;                         \
          u32 d0, d1, d2;                                                          \
          if (u == 0) { u32x2 t2 = *(const u32x2*)(pbc);                           \
                        d0 = t2.x; d1 = t2.y; d2 = *(const u32*)(pbc + 8); }       \
          else if (u == 1) { d0 = *(const u32*)(pbc + 12);                         \
                             u32x2 t2 = *(const u32x2*)(pbc + 16);                 \
                             d1 = t2.x; d2 = t2.y; }                               \
          else { u32x2 t2 = *(const u32x2*)(pbc + 24);                             \
                 d0 = t2.x; d1 = t2.y; d2 = 0; }                                   \
          u32x4 val = {d0, d1, d2, 7u};                                            \
          stg_tag(s0t + (emt * 32 + rowp) * 96 + nt * 3 + u, val);                 \
        }                                                                          \
      }                                                                            \
      const f16* wn = (v + 1 < 1024)                                               \
          ? wt_enc + ((long)(((v + 1) & 3) * 4 + eslot) << 21) + wslice            \
          : wt_enc + wslice;                                                       \
      asm volatile("" ::: "memory");                                               \
      _Pragma("unroll")                                                            \
      for (int kk = 0; kk < 16; ++kk) B[kk] = *(const f16x8*)(wn + kk * 512);      \
      WAVE_ORDER();                                                                \
    }                                                                              \
    END_STEP_ENC(TARGET);                                                          \
  } while (0)

__global__ __launch_bounds__(512, 2) void lstm_persist(
    const f16* __restrict__ xt,
    const f16* __restrict__ wt_enc, const f16* __restrict__ wt_dec,
    const float* __restrict__ enc_b, const float* __restrict__ dec_b,
    const float* __restrict__ enc_c0, const float* __restrict__ dec_c0,
    f16* __restrict__ h_enc, u32x4* __restrict__ hdt, u32x4* __restrict__ s0t,
    f16* __restrict__ ys, int* __restrict__ bar) {
  const int tid = threadIdx.x;
  const int lane = tid & 63;
  const int wid = tid >> 6;
  const int g = wid & 3;      // encoder: gate; decoder: K-slice-in-half
  const int kh = wid >> 2;    // K-half (enc & dec)
  const int col = lane & 15;
  const int kg = lane >> 4;
  const int idx = blockIdx.x;
  const int nt = idx & 31;
  const int n0 = nt << 4;
  const int eslot = idx >> 6;
  const int emt = (idx >> 5) & 1;
  const int dmt = idx >> 5;

  const int bflag = idx * 32;
  const int pe0 = ((((lane) >> 5) << 6) | (emt << 5) | (lane & 31)) * 32;
  const int pe1 = (((((lane + 64)) >> 5) << 6) | (emt << 5) | ((lane + 64) & 31)) * 32;

  __shared__ __align__(16) char AsBuf[65536];
  __shared__ float zredE[8][32][17];
  __shared__ float zredD[8][4][8][17];
  __shared__ float bias_enc_lds[256];
  __shared__ float bias_dec_lds[1024];
  __shared__ __align__(16) f16 pb16[512];

  const long wslice = ((long)(nt * 4 + g) * 2 + kh) * 8192 + lane * 8;
  const int HSz = BS * SH;

  for (int i = tid; i < 256; i += 512) {
    int L = i >> 6, gg = (i >> 4) & 3, ci = i & 15;
    bias_enc_lds[i] = enc_b[(L * 4 + eslot) * 2048 + gg * 512 + n0 + ci];
  }
  for (int i = tid; i < 1024; i += 512) {
    int cell = i >> 6, gg = (i >> 4) & 3, ci = i & 15;
    bias_dec_lds[i] = dec_b[cell * 2048 + gg * 512 + n0 + ci];
  }

  f16x8 B[16];
  {
    const f16* w = wt_enc + ((long)eslot << 21) + wslice;
#pragma unroll
    for (int kk = 0; kk < 16; ++kk) B[kk] = *(const f16x8*)(w + kk * 512);
  }
  __syncthreads();

  float ce = 0.f;
  float cd0 = 0.f, cd1 = 0.f, cd2 = 0.f, cd3 = 0.f;

  // -------- encoder: anti-diagonal wavefront (R10, barriered) --------
  for (int d = 0;; d += 2) {
    ENC_BODY(d, 0, d + 1);
    if (d == 1026) break;
    ENC_BODY(d + 1, 1, d + 2);
  }

  // -------- reload B for decoder cell 0 with 4-gate-per-wave slicing --------
#pragma unroll
  for (int g2 = 0; g2 < 4; ++g2)
#pragma unroll
    for (int kkl = 0; kkl < 4; ++kkl)
      B[g2 * 4 + kkl] = *(const f16x8*)(wt_dec +
          ((long)(nt * 4 + g2) * 2 + kh) * 8192 + (g * 4 + kkl) * 512 + lane * 8);

  // -------- decoder: pure dataflow, tag-fused handoff, no global barriers ----
  for (int s = 0; s < 4096; ++s) {
    const int vv = s >> 2, E = s & 3, par = vv & 1, L = vv & 3;
    const u32 T = 8u + (u32)s;
    const u32x4* inpT;
    if (E > 0) inpT = hdt + (par * 4 + E - 1) * SLAB;
    else if (vv > 0) inpT = hdt + ((par ^ 1) * 4 + 3) * SLAB;
    else inpT = s0t;
    const u32x4* hinT = hdt + ((par ^ 1) * 4 + E) * SLAB;

    // ---- poll + stage: 3 tagged units per thread ----
    {
      const int q1 = tid + 512;
      const int c1 = (q1 >= 768);
      const int l0 = tid, l1 = q1 - (c1 ? 768 : 0), l2 = tid + 256;
      const u32x4* a0 = inpT + dmt * 768 + l0;
      const u32x4* a1 = (c1 ? hinT : inpT) + dmt * 768 + l1;
      const u32x4* a2 = hinT + dmt * 768 + l2;
      const u32 e0 = T - 1, e1 = c1 ? T - 4 : T - 1, e2 = T - 4;
      u32x4 r0, r1, r2;
      for (;;) {
        r0 = ldg_tag(a0); r1 = ldg_tag(a1); r2 = ldg_tag(a2);
        VMCNT0();
        if (r0.w == e0 && r1.w == e1 && r2.w == e2) break;
        __builtin_amdgcn_s_sleep(2);
      }
      // unpack
      const u32x4 rr[3] = {r0, r1, r2};
      const int ll[3] = {l0, l1, l2};
      const int cc3[3] = {0, c1, 1};
#pragma unroll
      for (int j = 0; j < 3; ++j) {
        int row = ll[j] / 96;
        int rem = ll[j] - row * 96;
        int unt = rem / 3;
        int u = rem - unt * 3;
        char* A = AsBuf + cc3[j] * 8192 + SWZ(row, unt * 32);
        char* B2 = AsBuf + cc3[j] * 8192 + SWZ(row, unt * 32 + 16);
        u32x4 r = rr[j];
        if (u == 0) { u32x2 t2 = {r.x, r.y}; *(u32x2*)A = t2; *(u32*)(A + 8) = r.z; }
        else if (u == 1) { *(u32*)(A + 12) = r.x; u32x2 t2 = {r.y, r.z}; *(u32x2*)B2 = t2; }
        else { u32x2 t2 = {r.x, r.y}; *(u32x2*)(B2 + 8) = t2; }
      }
    }
    RAWBAR();

    // ---- MFMA: wave (kh, g=K-sub-slice): 4 gates x 4 kkl, A reused x4 ----
    f16x8 a_[4];
#pragma unroll
    for (int kkl = 0; kkl < 4; ++kkl)
      a_[kkl] = *(const f16x8*)(AsBuf + kh * 8192 +
                                SWZ(col & 7, g * 256 + kkl * 64 + kg * 16));
    f32x4 accg0 = 0.f, accg1 = 0.f, accg2 = 0.f, accg3 = 0.f;
#pragma unroll
    for (int kkl = 0; kkl < 4; ++kkl) {
      accg0 = __builtin_amdgcn_mfma_f32_16x16x32_f16(a_[kkl], B[0 * 4 + kkl], accg0, 0,0,0);
      accg1 = __builtin_amdgcn_mfma_f32_16x16x32_f16(a_[kkl], B[1 * 4 + kkl], accg1, 0,0,0);
      accg2 = __builtin_amdgcn_mfma_f32_16x16x32_f16(a_[kkl], B[2 * 4 + kkl], accg2, 0,0,0);
      accg3 = __builtin_amdgcn_mfma_f32_16x16x32_f16(a_[kkl], B[3 * 4 + kkl], accg3, 0,0,0);
    }
    if (kg < 2) {
#pragma unroll
      for (int r = 0; r < 4; ++r) {
        zredD[wid][0][kg * 4 + r][col] = accg0[r];
        zredD[wid][1][kg * 4 + r][col] = accg1[r];
        zredD[wid][2][kg * 4 + r][col] = accg2[r];
        zredD[wid][3][kg * 4 + r][col] = accg3[r];
      }
    }
    // weight prefetch for next cell (B dead after MFMA)
    if (s + 1 < 4096) {
      const int s2 = s + 1;
      const long cell2 = (long)((((s2 >> 2) & 3) * 4) + (s2 & 3));
      const f16* wb = wt_dec + (cell2 << 21);
      asm volatile("" ::: "memory");
#pragma unroll
      for (int g2 = 0; g2 < 4; ++g2)
#pragma unroll
        for (int kkl = 0; kkl < 4; ++kkl)
          B[g2 * 4 + kkl] = *(const f16x8*)(wb +
              ((long)(nt * 4 + g2) * 2 + kh) * 8192 + (g * 4 + kkl) * 512 + lane * 8);
    }
    RAWBAR();

    // ---- gate phase (tid<128): z sums, gates, c, h ----
    if (tid < 128) {
      const int row = tid >> 4, ci = tid & 15, n = n0 + ci;
      const float* bl = bias_dec_lds + (L * 4 + E) * 64 + ci;
      float zf = bl[0], zi = bl[16], zg = bl[32], zo = bl[48];
#pragma unroll
      for (int w = 0; w < 8; ++w) {
        zf += zredD[w][0][row][ci];
        zi += zredD[w][1][row][ci];
        zg += zredD[w][2][row][ci];
        zo += zredD[w][3][row][ci];
      }
      float f_ = sigmoidf_(zf), i_ = sigmoidf_(zi);
      float g_ = tanhf_(zg),   o_ = sigmoidf_(zo);
      float cin;
      if (vv == 0) cin = dec_c0[(long)E * HSz + (dmt * 8 + row) * SH + n];
      else cin = (E == 0) ? cd0 : (E == 1) ? cd1 : (E == 2) ? cd2 : cd3;
      float cc = f_ * cin + i_ * g_;
      if (E == 0) cd0 = cc; else if (E == 1) cd1 = cc;
      else if (E == 2) cd2 = cc; else cd3 = cc;
      float hv = o_ * tanhf_(cc);
      pb16[row * 16 + ci] = (f16)hv;
      if (E == 3) ys[((long)(dmt * 8 + row) * 1024 + vv) * SH + n] = (f16)hv;
    }
    RAWBAR();

    // ---- tagged h store (tid<24): pack 8 rows x 16 cols into 24 units ----
    if (tid < 24) {
      const int u = tid % 3, rowp = tid / 3;
      const char* pbc = (const char*)pb16 + rowp * 32;
      u32 d0, d1, d2;
      if (u == 0) { u32x2 t2 = *(const u32x2*)(pbc);
                    d0 = t2.x; d1 = t2.y; d2 = *(const u32*)(pbc + 8); }
      else if (u == 1) { d0 = *(const u32*)(pbc + 12);
                         u32x2 t2 = *(const u32x2*)(pbc + 16);
                         d1 = t2.x; d2 = t2.y; }
      else { u32x2 t2 = *(const u32x2*)(pbc + 24);
             d0 = t2.x; d1 = t2.y; d2 = 0; }
      u32x4 val = {d0, d1, d2, T};
      stg_tag(hdt + (par * 4 + E) * SLAB + (dmt * 8 + rowp) * 96 + nt * 3 + u, val);
    }
  }
}

// out[m][n] = sigmoid( ys[m][:] @ fint[n][:] + fin_b[n] )
__global__ __launch_bounds__(256) void final_gemm(const f16* __restrict__ ys,
                                                  const f16* __restrict__ fint,
                                                  const float* __restrict__ finb,
                                                  float* __restrict__ out) {
  const int lane = threadIdx.x & 63;
  const int w = threadIdx.x >> 6;
  const int col = lane & 15;
  const int kg = lane >> 4;
  const long m0 = (long)blockIdx.y * 64;
  const int n0 = (blockIdx.x * 4 + w) * 16;

  f32x4 acc[4];
#pragma unroll
  for (int mi = 0; mi < 4; ++mi) acc[mi] = 0.f;

#pragma unroll 2
  for (int kk = 0; kk < 16; ++kk) {
    f16x8 b = *(const f16x8*)(fint + (long)(n0 + col) * 512 + kk * 32 + kg * 8);
#pragma unroll
    for (int mi = 0; mi < 4; ++mi) {
      f16x8 a = *(const f16x8*)(ys + (m0 + mi * 16 + col) * 512 + kk * 32 + kg * 8);
      acc[mi] = __builtin_amdgcn_mfma_f32_16x16x32_f16(a, b, acc[mi], 0, 0, 0);
    }
  }
  const int n = n0 + col;
  const float bn = finb[n];
#pragma unroll
  for (int mi = 0; mi < 4; ++mi)
#pragma unroll
    for (int r = 0; r < 4; ++r)
      out[(m0 + mi * 16 + kg * 4 + r) * 512 + n] = sigmoidf_(acc[mi][r] + bn);
}

extern "C" void kernel_launch(void* const* d_in, const int* in_sizes, int n_in,
                              void* d_out, int out_size, void* d_ws, size_t ws_size,
                              hipStream_t stream) {
  const float* x      = (const float*)d_in[0];
  const float* enc_W  = (const float*)d_in[2];
  const float* enc_V  = (const float*)d_in[3];
  const float* enc_b  = (const float*)d_in[4];
  const float* enc_h0 = (const float*)d_in[5];
  const float* enc_c0 = (const float*)d_in[6];
  const float* dec_W  = (const float*)d_in[7];
  const float* dec_V  = (const float*)d_in[8];
  const float* dec_b  = (const float*)d_in[9];
  const float* dec_h0 = (const float*)d_in[10];
  const float* dec_c0 = (const float*)d_in[11];
  const float* fin_W  = (const float*)d_in[12];
  const float* fin_b  = (const float*)d_in[13];
  float* out = (float*)d_out;

  // workspace layout
  f16* wt_enc = (f16*)d_ws;                                   // 16*2048*1024
  f16* wt_dec = wt_enc + (long)16 * 2048 * 1024;              // 16*2048*1024
  f16* xt     = wt_dec + (long)16 * 2048 * 1024;              // 256*64*512
  f16* fint   = xt + (long)SL * BS * SI;                      // 512*512
  f16* ys     = fint + (long)SH * SI;                         // 64*1024*512
  f16* h_enc  = ys + (long)BS * (FL * 4) * SH;                // 2*4*64*512
  f16* h_unused = h_enc + (long)2 * 4 * BS * SH;              // reserved
  float* c_unused = (float*)(h_unused + (long)2 * 4 * BS * SH);
  int* bar = (int*)(c_unused + (long)8 * BS * SH);            // 256 flags x 128B
  u32x4* hdt = (u32x4*)((char*)bar + 65536);                  // 8 slabs x 6144 units
  u32x4* s0t = hdt + 8 * SLAB;                                // 6144 units

  hipMemsetAsync(bar, 0, 65536, stream);
  hipMemsetAsync(hdt, 0, (size_t)(8 * SLAB + SLAB) * 16, stream);

  conv_w<<<131072, 256, 0, stream>>>(enc_W, enc_V, wt_enc);
  conv_w<<<131072, 256, 0, stream>>>(dec_W, dec_V, wt_dec);
  conv_x<<<32768, 256, 0, stream>>>(x, xt);
  conv_fin<<<1024, 256, 0, stream>>>(fin_W, fint);
  init_state<<<512, 256, 0, stream>>>(enc_h0, h_enc);
  init_dec_tags<<<96, 256, 0, stream>>>(dec_h0, hdt);

  lstm_persist<<<NBLK, 512, 0, stream>>>(xt, wt_enc, wt_dec, enc_b, dec_b,
                                         enc_c0, dec_c0, h_enc, hdt, s0t, ys, bar);

  dim3 fg(8, 1024);
  final_gemm<<<fg, 256, 0, stream>>>(ys, fint, fin_b, out);
}

// Round 12
// 24768.130 us; speedup vs baseline: 1.0010x; 1.0010x over previous
//
#include <hip/hip_runtime.h>

typedef _Float16 f16;
typedef _Float16 f16x8 __attribute__((ext_vector_type(8)));
typedef float f32x4 __attribute__((ext_vector_type(4)));
typedef unsigned int u32;
typedef u32 u32x4 __attribute__((ext_vector_type(4)));
typedef u32 u32x2 __attribute__((ext_vector_type(2)));

#define BS 64
#define SL 256
#define FL 256
#define SI 512
#define SH 512
#define NBLK 256
#define SLAB 6144   // units (16B) per tagged h slab: 64 rows x 32 nt x 3 u

__device__ __forceinline__ float sigmoidf_(float x) { return 1.f / (1.f + __expf(-x)); }
__device__ __forceinline__ float tanhf_(float x) { float e = __expf(2.f * x); return 1.f - 2.f / (e + 1.f); }

__device__ __forceinline__ f16x8 ldg_cohere(const f16* p) {
  f16x8 r;
  asm volatile("global_load_dwordx4 %0, %1, off sc0 sc1" : "=v"(r) : "v"(p) : "memory");
  return r;
}
__device__ __forceinline__ u32x4 ldg_tag(const u32x4* p) {
  u32x4 r;
  asm volatile("global_load_dwordx4 %0, %1, off sc0 sc1" : "=v"(r) : "v"(p) : "memory");
  return r;
}
__device__ __forceinline__ void stg_tag(u32x4* p, u32x4 v) {
  asm volatile("global_store_dwordx4 %0, %1, off sc0 sc1" :: "v"(p), "v"(v) : "memory");
}

// Weights packed in MFMA-fragment order (unchanged):
// n = g*512 + nt*16 + (lane&15), k = kh*512 + kk*32 + (lane>>4)*8 + j
__global__ void conv_w(const float* __restrict__ W, const float* __restrict__ V,
                       f16* __restrict__ out) {
  long idx = (long)blockIdx.x * blockDim.x + threadIdx.x;  // total 2^25
  int j    = (int)(idx & 7);
  int lane = (int)((idx >> 3) & 63);
  int kk   = (int)((idx >> 9) & 15);
  int kh   = (int)((idx >> 13) & 1);
  int g    = (int)((idx >> 14) & 3);
  int nt   = (int)((idx >> 16) & 31);
  long cell = idx >> 21;
  int n = g * 512 + nt * 16 + (lane & 15);
  int k = kh * 512 + kk * 32 + (lane >> 4) * 8 + j;
  float v = (k < 512) ? W[(cell * 512 + k) * 2048 + n]
                      : V[(cell * 512 + (k - 512)) * 2048 + n];
  out[idx] = (f16)v;
}

__global__ void conv_x(const float* __restrict__ x, f16* __restrict__ xt) {
  long idx = (long)blockIdx.x * blockDim.x + threadIdx.x;  // 256*64*512
  int i = (int)(idx & 511);
  int b = (int)((idx >> 9) & 63);
  int t = (int)(idx >> 15);
  xt[idx] = (f16)x[((long)b * SL + t) * SI + i];
}

__global__ void conv_fin(const float* __restrict__ finW, f16* __restrict__ fint) {
  long idx = (long)blockIdx.x * blockDim.x + threadIdx.x;  // 512*512
  int k = (int)(idx & 511);
  int n = (int)(idx >> 9);
  fint[idx] = (f16)finW[(long)k * SI + n];
}

// h_enc both parities = enc_h0 (encoder keeps dense format)
__global__ void init_state(const float* __restrict__ h0e, f16* __restrict__ h_enc) {
  long idx = (long)blockIdx.x * blockDim.x + threadIdx.x;  // 131072
  f16 he = (f16)h0e[idx];
  h_enc[idx] = he;
  h_enc[idx + 131072] = he;
}

// dec_h0 -> tagged units in par=1 slabs, tag = 4+E (acts as step T(v=-1,E))
__global__ void init_dec_tags(const float* __restrict__ h0d, u32x4* __restrict__ hdt) {
  int i = blockIdx.x * blockDim.x + threadIdx.x;  // 4*64*96 = 24576
  int E = i / 6144;
  int r = i - E * 6144;
  int row = r / 96;
  int rem = r - row * 96;
  int unt = rem / 3;
  int u = rem - unt * 3;
  int c0 = unt * 16 + u * 6;
  const float* src = h0d + (long)E * 32768 + row * 512 + c0;
  u32 d[3] = {0, 0, 0};
  int count = (u == 2) ? 4 : 6;
  for (int k = 0; k < count; k += 2) {
    f16 a = (f16)src[k], b = (f16)src[k + 1];
    d[k >> 1] = (u32)__builtin_bit_cast(unsigned short, a) |
                ((u32)__builtin_bit_cast(unsigned short, b) << 16);
  }
  u32x4 val = {d[0], d[1], d[2], (u32)(4 + E)};
  hdt[(4 + E) * SLAB + r] = val;
}

__device__ __forceinline__ void store_h_agent(f16* p, float v) {
  f16 h = (f16)v;
  __hip_atomic_store((unsigned short*)p, __builtin_bit_cast(unsigned short, h),
                     __ATOMIC_RELAXED, __HIP_MEMORY_SCOPE_AGENT);
}

#define SWZ(ROW, BOFF) (((ROW) << 10) + ((BOFF) ^ ((((ROW) & 7)) << 4)))

#define VMCNT0() do {                                                             \
    asm volatile("s_waitcnt vmcnt(0)" ::: "memory");                              \
    __builtin_amdgcn_sched_barrier(0);                                            \
  } while (0)

#define RAWBAR() do {                                                             \
    asm volatile("s_waitcnt lgkmcnt(0)" ::: "memory");                            \
    __builtin_amdgcn_sched_barrier(0);                                            \
    __builtin_amdgcn_s_barrier();                                                 \
    __builtin_amdgcn_sched_barrier(0);                                            \
  } while (0)

#define WAVE_ORDER() do {                                                          \
    asm volatile("s_waitcnt vmcnt(16)" ::: "memory");                              \
    __builtin_amdgcn_sched_barrier(0);                                             \
  } while (0)

// Encoder group barrier (128 blocks sharing emt) — unchanged from R10.
#define END_STEP_ENC(TARGET) do {                                                  \
    __builtin_amdgcn_s_barrier();                                                  \
    asm volatile("" ::: "memory");                                                 \
    if (tid == 0)                                                                  \
      __hip_atomic_store(&bar[bflag], (TARGET), __ATOMIC_RELAXED,                  \
                         __HIP_MEMORY_SCOPE_AGENT);                                \
    if (wid == 0) {                                                                \
      for (;;) {                                                                   \
        int a0 = __hip_atomic_load(&bar[pe0], __ATOMIC_RELAXED,                    \
                                   __HIP_MEMORY_SCOPE_AGENT);                      \
        int a1 = __hip_atomic_load(&bar[pe1], __ATOMIC_RELAXED,                    \
                                   __HIP_MEMORY_SCOPE_AGENT);                      \
        if (a0 >= (TARGET) && a1 >= (TARGET)) break;                               \
        __builtin_amdgcn_s_sleep(1);                                               \
      }                                                                            \
    }                                                                              \
    __builtin_amdgcn_s_barrier();                                                  \
    asm volatile("" ::: "memory");                                                 \
    __builtin_amdgcn_sched_barrier(0);                                             \
  } while (0)

// Encoder body (R10 structure) + one-time tagged state0 emission at v==1023.
#define ENC_BODY(DD, P, TARGET) do {                                               \
    const int v = (DD) - eslot;                                                    \
    if (v >= 0 && v < 1024) {                                                      \
      const int L = v & 3, t = v >> 2;                                             \
      const f16* inp = (eslot == 0) ? (xt + (long)t * HSz)                         \
                                    : (h_enc + ((P)*4 + (eslot - 1)) * HSz);       \
      const f16* hin = h_enc + ((P)*4 + eslot) * HSz;                              \
      f16* hout = h_enc + ((1 - (P))*4 + eslot) * HSz;                             \
      {                                                                            \
        const f16* c0p = inp + emt * 16384;                                        \
        const f16* c1p = hin + emt * 16384;                                        \
        f16x8 tr[8];                                                               \
        _Pragma("unroll")                                                          \
        for (int k2 = 0; k2 < 4; ++k2) {                                           \
          const int s2 = tid + k2 * 512, row = s2 >> 6, c16 = s2 & 63;             \
          tr[k2]     = ldg_cohere(c0p + row * 512 + c16 * 8);                      \
          tr[k2 + 4] = ldg_cohere(c1p + row * 512 + c16 * 8);                      \
        }                                                                          \
        VMCNT0();                                                                  \
        _Pragma("unroll")                                                          \
        for (int k2 = 0; k2 < 4; ++k2) {                                           \
          const int s2 = tid + k2 * 512, row = s2 >> 6, c16 = s2 & 63;             \
          *(f16x8*)(AsBuf + SWZ(row, c16 * 16)) = tr[k2];                          \
          *(f16x8*)(AsBuf + 32768 + SWZ(row, c16 * 16)) = tr[k2 + 4];              \
        }                                                                          \
      }                                                                            \
      RAWBAR();                                                                    \
      f32x4 acc0 = 0.f, acc1 = 0.f;                                                \
      _Pragma("unroll")                                                            \
      for (int kk = 0; kk < 16; ++kk) {                                            \
        f16x8 a0 = *(const f16x8*)(AsBuf + kh * 32768 +                            \
                                   SWZ(col, kk * 64 + kg * 16));                   \
        f16x8 a1 = *(const f16x8*)(AsBuf + kh * 32768 +                            \
                                   SWZ(col + 16, kk * 64 + kg * 16));              \
        acc0 = __builtin_amdgcn_mfma_f32_16x16x32_f16(a0, B[kk], acc0, 0,0,0);     \
        acc1 = __builtin_amdgcn_mfma_f32_16x16x32_f16(a1, B[kk], acc1, 0,0,0);     \
      }                                                                            \
      _Pragma("unroll")                                                            \
      for (int r = 0; r < 4; ++r) {                                                \
        zredE[wid][kg*4 + r][col] = acc0[r];                                       \
        zredE[wid][16 + kg*4 + r][col] = acc1[r];                                  \
      }                                                                            \
      RAWBAR();                                                                    \
      const bool s0f = (v == 1023) && (eslot == 3);                                \
      {                                                                            \
        const int row = tid >> 4, ci = tid & 15, n = n0 + ci;                      \
        const float* bl = bias_enc_lds + L * 64 + ci;                              \
        float zf = bl[0]  + zredE[0][row][ci] + zredE[4][row][ci];                 \
        float zi = bl[16] + zredE[1][row][ci] + zredE[5][row][ci];                 \
        float zg = bl[32] + zredE[2][row][ci] + zredE[6][row][ci];                 \
        float zo = bl[48] + zredE[3][row][ci] + zredE[7][row][ci];                 \
        float f_ = sigmoidf_(zf), i_ = sigmoidf_(zi);                              \
        float g_ = tanhf_(zg),   o_ = sigmoidf_(zo);                               \
        const int grow = emt * 32 + row;                                           \
        float cin = (v == 0) ? enc_c0[(long)eslot * HSz + grow * SH + n] : ce;     \
        float cc = f_ * cin + i_ * g_;                                             \
        ce = cc;                                                                   \
        float hv = o_ * tanhf_(cc);                                                \
        store_h_agent(hout + grow * SH + n, hv);                                   \
        if (s0f) pb16[row * 16 + ci] = (f16)hv;                                    \
      }                                                                            \
      if (s0f) {                                                                   \
        RAWBAR();                                                                  \
        if (tid < 96) {                                                            \
          int u = tid % 3, rowp = tid / 3;                                         \
          const char* pbc = (const char*)pb16 + rowp * 32;                         \
          u32 d0, d1, d2;                                                          \
          if (u == 0) { u32x2 t2 = *(const u32x2*)(pbc);                           \
                        d0 = t2.x; d1 = t2.y; d2 = *(const u32*)(pbc + 8); }       \
          else if (u == 1) { d0 = *(const u32*)(pbc + 12);                         \
                             u32x2 t2 = *(const u32x2*)(pbc + 16);                 \
                             d1 = t2.x; d2 = t2.y; }                               \
          else { u32x2 t2 = *(const u32x2*)(pbc + 24);                             \
                 d0 = t2.x; d1 = t2.y; d2 = 0; }                                   \
          u32x4 val = {d0, d1, d2, 7u};                                            \
          stg_tag(s0t + (emt * 32 + rowp) * 96 + nt * 3 + u, val);                 \
        }                                                                          \
      }                                                                            \
      const f16* wn = (v + 1 < 1024)                                               \
          ? wt_enc + ((long)(((v + 1) & 3) * 4 + eslot) << 21) + wslice            \
          : wt_enc + wslice;                                                       \
      asm volatile("" ::: "memory");                                               \
      _Pragma("unroll")                                                            \
      for (int kk = 0; kk < 16; ++kk) B[kk] = *(const f16x8*)(wn + kk * 512);      \
      WAVE_ORDER();                                                                \
    }                                                                              \
    END_STEP_ENC(TARGET);                                                          \
  } while (0)

__global__ __launch_bounds__(512, 2) void lstm_persist(
    const f16* __restrict__ xt,
    const f16* __restrict__ wt_enc, const f16* __restrict__ wt_dec,
    const float* __restrict__ enc_b, const float* __restrict__ dec_b,
    const float* __restrict__ enc_c0, const float* __restrict__ dec_c0,
    f16* __restrict__ h_enc, u32x4* __restrict__ hdt, u32x4* __restrict__ s0t,
    f16* __restrict__ ys, int* __restrict__ bar) {
  const int tid = threadIdx.x;
  const int lane = tid & 63;
  const int wid = tid >> 6;
  const int g = wid & 3;      // encoder: gate; decoder: K-slice-in-half
  const int kh = wid >> 2;    // K-half (enc & dec)
  const int col = lane & 15;
  const int kg = lane >> 4;
  const int idx = blockIdx.x;
  const int nt = idx & 31;
  const int n0 = nt << 4;
  const int eslot = idx >> 6;
  const int emt = (idx >> 5) & 1;
  const int dmt = idx >> 5;

  const int bflag = idx * 32;
  const int pe0 = ((((lane) >> 5) << 6) | (emt << 5) | (lane & 31)) * 32;
  const int pe1 = (((((lane + 64)) >> 5) << 6) | (emt << 5) | ((lane + 64) & 31)) * 32;

  __shared__ __align__(16) char AsBuf[65536];
  __shared__ float zredE[8][32][17];
  __shared__ float zredD[8][4][8][17];
  __shared__ float bias_enc_lds[256];
  __shared__ float bias_dec_lds[1024];
  __shared__ __align__(16) f16 pb16[512];

  const long wslice = ((long)(nt * 4 + g) * 2 + kh) * 8192 + lane * 8;
  const int HSz = BS * SH;

  for (int i = tid; i < 256; i += 512) {
    int L = i >> 6, gg = (i >> 4) & 3, ci = i & 15;
    bias_enc_lds[i] = enc_b[(L * 4 + eslot) * 2048 + gg * 512 + n0 + ci];
  }
  for (int i = tid; i < 1024; i += 512) {
    int cell = i >> 6, gg = (i >> 4) & 3, ci = i & 15;
    bias_dec_lds[i] = dec_b[cell * 2048 + gg * 512 + n0 + ci];
  }

  f16x8 B[16];
  {
    const f16* w = wt_enc + ((long)eslot << 21) + wslice;
#pragma unroll
    for (int kk = 0; kk < 16; ++kk) B[kk] = *(const f16x8*)(w + kk * 512);
  }
  __syncthreads();

  float ce = 0.f;
  float cd0 = 0.f, cd1 = 0.f, cd2 = 0.f, cd3 = 0.f;

  // -------- encoder: anti-diagonal wavefront (R10, barriered) --------
  for (int d = 0;; d += 2) {
    ENC_BODY(d, 0, d + 1);
    if (d == 1026) break;
    ENC_BODY(d + 1, 1, d + 2);
  }

  // -------- reload B for decoder cell 0 with 4-gate-per-wave slicing --------
#pragma unroll
  for (int g2 = 0; g2 < 4; ++g2)
#pragma unroll
    for (int kkl = 0; kkl < 4; ++kkl)
      B[g2 * 4 + kkl] = *(const f16x8*)(wt_dec +
          ((long)(nt * 4 + g2) * 2 + kh) * 8192 + (g * 4 + kkl) * 512 + lane * 8);

  // -------- decoder: pure dataflow, tag-fused handoff, no global barriers ----
  for (int s = 0; s < 4096; ++s) {
    const int vv = s >> 2, E = s & 3, par = vv & 1, L = vv & 3;
    const u32 T = 8u + (u32)s;
    const u32x4* inpT;
    if (E > 0) inpT = hdt + (par * 4 + E - 1) * SLAB;
    else if (vv > 0) inpT = hdt + ((par ^ 1) * 4 + 3) * SLAB;
    else inpT = s0t;
    const u32x4* hinT = hdt + ((par ^ 1) * 4 + E) * SLAB;

    // ---- poll + stage: 3 tagged units per thread ----
    {
      const int q1 = tid + 512;
      const int c1 = (q1 >= 768);
      const int l0 = tid, l1 = q1 - (c1 ? 768 : 0), l2 = tid + 256;
      const u32x4* a0 = inpT + dmt * 768 + l0;
      const u32x4* a1 = (c1 ? hinT : inpT) + dmt * 768 + l1;
      const u32x4* a2 = hinT + dmt * 768 + l2;
      const u32 e0 = T - 1, e1 = c1 ? T - 4 : T - 1, e2 = T - 4;
      u32x4 r0, r1, r2;
      for (;;) {
        r0 = ldg_tag(a0); r1 = ldg_tag(a1); r2 = ldg_tag(a2);
        VMCNT0();
        if (r0.w == e0 && r1.w == e1 && r2.w == e2) break;
        __builtin_amdgcn_s_sleep(2);
      }
      // unpack
      const u32x4 rr[3] = {r0, r1, r2};
      const int ll[3] = {l0, l1, l2};
      const int cc3[3] = {0, c1, 1};
#pragma unroll
      for (int j = 0; j < 3; ++j) {
        int row = ll[j] / 96;
        int rem = ll[j] - row * 96;
        int unt = rem / 3;
        int u = rem - unt * 3;
        char* A = AsBuf + cc3[j] * 8192 + SWZ(row, unt * 32);
        char* B2 = AsBuf + cc3[j] * 8192 + SWZ(row, unt * 32 + 16);
        u32x4 r = rr[j];
        if (u == 0) { u32x2 t2 = {r.x, r.y}; *(u32x2*)A = t2; *(u32*)(A + 8) = r.z; }
        else if (u == 1) { *(u32*)(A + 12) = r.x; u32x2 t2 = {r.y, r.z}; *(u32x2*)B2 = t2; }
        else { u32x2 t2 = {r.x, r.y}; *(u32x2*)(B2 + 8) = t2; }
      }
    }
    RAWBAR();

    // ---- MFMA: wave (kh, g=K-sub-slice): 4 gates x 4 kkl, A reused x4 ----
    f16x8 a_[4];
#pragma unroll
    for (int kkl = 0; kkl < 4; ++kkl)
      a_[kkl] = *(const f16x8*)(AsBuf + kh * 8192 +
                                SWZ(col & 7, g * 256 + kkl * 64 + kg * 16));
    f32x4 accg0 = 0.f, accg1 = 0.f, accg2 = 0.f, accg3 = 0.f;
#pragma unroll
    for (int kkl = 0; kkl < 4; ++kkl) {
      accg0 = __builtin_amdgcn_mfma_f32_16x16x32_f16(a_[kkl], B[0 * 4 + kkl], accg0, 0,0,0);
      accg1 = __builtin_amdgcn_mfma_f32_16x16x32_f16(a_[kkl], B[1 * 4 + kkl], accg1, 0,0,0);
      accg2 = __builtin_amdgcn_mfma_f32_16x16x32_f16(a_[kkl], B[2 * 4 + kkl], accg2, 0,0,0);
      accg3 = __builtin_amdgcn_mfma_f32_16x16x32_f16(a_[kkl], B[3 * 4 + kkl], accg3, 0,0,0);
    }
    if (kg < 2) {
#pragma unroll
      for (int r = 0; r < 4; ++r) {
        zredD[wid][0][kg * 4 + r][col] = accg0[r];
        zredD[wid][1][kg * 4 + r][col] = accg1[r];
        zredD[wid][2][kg * 4 + r][col] = accg2[r];
        zredD[wid][3][kg * 4 + r][col] = accg3[r];
      }
    }
    // weight prefetch for next cell (B dead after MFMA)
    if (s + 1 < 4096) {
      const int s2 = s + 1;
      const long cell2 = (long)((((s2 >> 2) & 3) * 4) + (s2 & 3));
      const f16* wb = wt_dec + (cell2 << 21);
      asm volatile("" ::: "memory");
#pragma unroll
      for (int g2 = 0; g2 < 4; ++g2)
#pragma unroll
        for (int kkl = 0; kkl < 4; ++kkl)
          B[g2 * 4 + kkl] = *(const f16x8*)(wb +
              ((long)(nt * 4 + g2) * 2 + kh) * 8192 + (g * 4 + kkl) * 512 + lane * 8);
    }
    RAWBAR();

    // ---- gate phase (tid<128): z sums, gates, c, h ----
    if (tid < 128) {
      const int row = tid >> 4, ci = tid & 15, n = n0 + ci;
      const float* bl = bias_dec_lds + (L * 4 + E) * 64 + ci;
      float zf = bl[0], zi = bl[16], zg = bl[32], zo = bl[48];
#pragma unroll
      for (int w = 0; w < 8; ++w) {
        zf += zredD[w][0][row][ci];
        zi += zredD[w][1][row][ci];
        zg += zredD[w][2][row][ci];
        zo += zredD[w][3][row][ci];
      }
      float f_ = sigmoidf_(zf), i_ = sigmoidf_(zi);
      float g_ = tanhf_(zg),   o_ = sigmoidf_(zo);
      float cin;
      if (vv == 0) cin = dec_c0[(long)E * HSz + (dmt * 8 + row) * SH + n];
      else cin = (E == 0) ? cd0 : (E == 1) ? cd1 : (E == 2) ? cd2 : cd3;
      float cc = f_ * cin + i_ * g_;
      if (E == 0) cd0 = cc; else if (E == 1) cd1 = cc;
      else if (E == 2) cd2 = cc; else cd3 = cc;
      float hv = o_ * tanhf_(cc);
      pb16[row * 16 + ci] = (f16)hv;
      if (E == 3) ys[((long)(dmt * 8 + row) * 1024 + vv) * SH + n] = (f16)hv;
    }
    RAWBAR();

    // ---- tagged h store (tid<24): pack 8 rows x 16 cols into 24 units ----
    if (tid < 24) {
      const int u = tid % 3, rowp = tid / 3;
      const char* pbc = (const char*)pb16 + rowp * 32;
      u32 d0, d1, d2;
      if (u == 0) { u32x2 t2 = *(const u32x2*)(pbc);
                    d0 = t2.x; d1 = t2.y; d2 = *(const u32*)(pbc + 8); }
      else if (u == 1) { d0 = *(const u32*)(pbc + 12);
                         u32x2 t2 = *(const u32x2*)(pbc + 16);
                         d1 = t2.x; d2 = t2.y; }
      else { u32x2 t2 = *(const u32x2*)(pbc + 24);
             d0 = t2.x; d1 = t2.y; d2 = 0; }
      u32x4 val = {d0, d1, d2, T};
      stg_tag(hdt + (par * 4 + E) * SLAB + (dmt * 8 + rowp) * 96 + nt * 3 + u, val);
    }
  }
}

// out[m][n] = sigmoid( ys[m][:] @ fint[n][:] + fin_b[n] )
__global__ __launch_bounds__(256) void final_gemm(const f16* __restrict__ ys,
                                                  const f16* __restrict__ fint,
                                                  const float* __restrict__ finb,
                                                  float* __restrict__ out) {
  const int lane = threadIdx.x & 63;
  const int w = threadIdx.x >> 6;
  const int col = lane & 15;
  const int kg = lane >> 4;
  const long m0 = (long)blockIdx.y * 64;
  const int n0 = (blockIdx.x * 4 + w) * 16;

  f32x4 acc[4];
#pragma unroll
  for (int mi = 0; mi < 4; ++mi) acc[mi] = 0.f;

#pragma unroll 2
  for (int kk = 0; kk < 16; ++kk) {
    f16x8 b = *(const f16x8*)(fint + (long)(n0 + col) * 512 + kk * 32 + kg * 8);
#pragma unroll
    for (int mi = 0; mi < 4; ++mi) {
      f16x8 a = *(const f16x8*)(ys + (m0 + mi * 16 + col) * 512 + kk * 32 + kg * 8);
      acc[mi] = __builtin_amdgcn_mfma_f32_16x16x32_f16(a, b, acc[mi], 0, 0, 0);
    }
  }
  const int n = n0 + col;
  const float bn = finb[n];
#pragma unroll
  for (int mi = 0; mi < 4; ++mi)
#pragma unroll
    for (int r = 0; r < 4; ++r)
      out[(m0 + mi * 16 + kg * 4 + r) * 512 + n] = sigmoidf_(acc[mi][r] + bn);
}

extern "C" void kernel_launch(void* const* d_in, const int* in_sizes, int n_in,
                              void* d_out, int out_size, void* d_ws, size_t ws_size,
                              hipStream_t stream) {
  const float* x      = (const float*)d_in[0];
  const float* enc_W  = (const float*)d_in[2];
  const float* enc_V  = (const float*)d_in[3];
  const float* enc_b  = (const float*)d_in[4];
  const float* enc_h0 = (const float*)d_in[5];
  const float* enc_c0 = (const float*)d_in[6];
  const float* dec_W  = (const float*)d_in[7];
  const float* dec_V  = (const float*)d_in[8];
  const float* dec_b  = (const float*)d_in[9];
  const float* dec_h0 = (const float*)d_in[10];
  const float* dec_c0 = (const float*)d_in[11];
  const float* fin_W  = (const float*)d_in[12];
  const float* fin_b  = (const float*)d_in[13];
  float* out = (float*)d_out;

  // workspace layout
  f16* wt_enc = (f16*)d_ws;                                   // 16*2048*1024
  f16* wt_dec = wt_enc + (long)16 * 2048 * 1024;              // 16*2048*1024
  f16* xt     = wt_dec + (long)16 * 2048 * 1024;              // 256*64*512
  f16* fint   = xt + (long)SL * BS * SI;                      // 512*512
  f16* ys     = fint + (long)SH * SI;                         // 64*1024*512
  f16* h_enc  = ys + (long)BS * (FL * 4) * SH;                // 2*4*64*512
  f16* h_unused = h_enc + (long)2 * 4 * BS * SH;              // reserved
  float* c_unused = (float*)(h_unused + (long)2 * 4 * BS * SH);
  int* bar = (int*)(c_unused + (long)8 * BS * SH);            // 256 flags x 128B
  u32x4* hdt = (u32x4*)((char*)bar + 65536);                  // 8 slabs x 6144 units
  u32x4* s0t = hdt + 8 * SLAB;                                // 6144 units

  hipMemsetAsync(bar, 0, 65536, stream);
  hipMemsetAsync(hdt, 0, (size_t)(8 * SLAB + SLAB) * 16, stream);

  conv_w<<<131072, 256, 0, stream>>>(enc_W, enc_V, wt_enc);
  conv_w<<<131072, 256, 0, stream>>>(dec_W, dec_V, wt_dec);
  conv_x<<<32768, 256, 0, stream>>>(x, xt);
  conv_fin<<<1024, 256, 0, stream>>>(fin_W, fint);
  init_state<<<512, 256, 0, stream>>>(enc_h0, h_enc);
  init_dec_tags<<<96, 256, 0, stream>>>(dec_h0, hdt);

  lstm_persist<<<NBLK, 512, 0, stream>>>(xt, wt_enc, wt_dec, enc_b, dec_b,
                                         enc_c0, dec_c0, h_enc, hdt, s0t, ys, bar);

  dim3 fg(8, 1024);
  final_gemm<<<fg, 256, 0, stream>>>(ys, fint, fin_b, out);
}

// Round 13
// 24763.786 us; speedup vs baseline: 1.0011x; 1.0002x over previous
//
#include <hip/hip_runtime.h>

typedef _Float16 f16;
typedef _Float16 f16x8 __attribute__((ext_vector_type(8)));
typedef float f32x4 __attribute__((ext_vector_type(4)));
typedef unsigned int u32;
typedef u32 u32x4 __attribute__((ext_vector_type(4)));
typedef u32 u32x2 __attribute__((ext_vector_type(2)));

#define BS 64
#define SL 256
#define FL 256
#define SI 512
#define SH 512
#define NBLK 256
#define SLAB 6144   // units (16B) per tagged h slab: 64 rows x 32 nt x 3 u

__device__ __forceinline__ float sigmoidf_(float x) { return 1.f / (1.f + __expf(-x)); }
__device__ __forceinline__ float tanhf_(float x) { float e = __expf(2.f * x); return 1.f - 2.f / (e + 1.f); }

__device__ __forceinline__ f16x8 ldg_cohere(const f16* p) {
  f16x8 r;
  asm volatile("global_load_dwordx4 %0, %1, off sc0 sc1" : "=v"(r) : "v"(p) : "memory");
  return r;
}
__device__ __forceinline__ u32x4 ldg_tag(const u32x4* p) {
  u32x4 r;
  asm volatile("global_load_dwordx4 %0, %1, off sc0 sc1" : "=v"(r) : "v"(p) : "memory");
  return r;
}
__device__ __forceinline__ void stg_tag(u32x4* p, u32x4 v) {
  asm volatile("global_store_dwordx4 %0, %1, off sc0 sc1" :: "v"(p), "v"(v) : "memory");
}

// Weights packed in MFMA-fragment order (unchanged):
// n = g*512 + nt*16 + (lane&15), k = kh*512 + kk*32 + (lane>>4)*8 + j
__global__ void conv_w(const float* __restrict__ W, const float* __restrict__ V,
                       f16* __restrict__ out) {
  long idx = (long)blockIdx.x * blockDim.x + threadIdx.x;  // total 2^25
  int j    = (int)(idx & 7);
  int lane = (int)((idx >> 3) & 63);
  int kk   = (int)((idx >> 9) & 15);
  int kh   = (int)((idx >> 13) & 1);
  int g    = (int)((idx >> 14) & 3);
  int nt   = (int)((idx >> 16) & 31);
  long cell = idx >> 21;
  int n = g * 512 + nt * 16 + (lane & 15);
  int k = kh * 512 + kk * 32 + (lane >> 4) * 8 + j;
  float v = (k < 512) ? W[(cell * 512 + k) * 2048 + n]
                      : V[(cell * 512 + (k - 512)) * 2048 + n];
  out[idx] = (f16)v;
}

__global__ void conv_x(const float* __restrict__ x, f16* __restrict__ xt) {
  long idx = (long)blockIdx.x * blockDim.x + threadIdx.x;  // 256*64*512
  int i = (int)(idx & 511);
  int b = (int)((idx >> 9) & 63);
  int t = (int)(idx >> 15);
  xt[idx] = (f16)x[((long)b * SL + t) * SI + i];
}

__global__ void conv_fin(const float* __restrict__ finW, f16* __restrict__ fint) {
  long idx = (long)blockIdx.x * blockDim.x + threadIdx.x;  // 512*512
  int k = (int)(idx & 511);
  int n = (int)(idx >> 9);
  fint[idx] = (f16)finW[(long)k * SI + n];
}

// h_enc both parities = enc_h0 (encoder keeps dense format)
__global__ void init_state(const float* __restrict__ h0e, f16* __restrict__ h_enc) {
  long idx = (long)blockIdx.x * blockDim.x + threadIdx.x;  // 131072
  f16 he = (f16)h0e[idx];
  h_enc[idx] = he;
  h_enc[idx + 131072] = he;
}

// dec_h0 -> tagged units in par=1 slabs, tag = 4+E (acts as step T(v=-1,E))
__global__ void init_dec_tags(const float* __restrict__ h0d, u32x4* __restrict__ hdt) {
  int i = blockIdx.x * blockDim.x + threadIdx.x;  // 4*64*96 = 24576
  int E = i / 6144;
  int r = i - E * 6144;
  int row = r / 96;
  int rem = r - row * 96;
  int unt = rem / 3;
  int u = rem - unt * 3;
  int c0 = unt * 16 + u * 6;
  const float* src = h0d + (long)E * 32768 + row * 512 + c0;
  u32 d[3] = {0, 0, 0};
  int count = (u == 2) ? 4 : 6;
  for (int k = 0; k < count; k += 2) {
    f16 a = (f16)src[k], b = (f16)src[k + 1];
    d[k >> 1] = (u32)__builtin_bit_cast(unsigned short, a) |
                ((u32)__builtin_bit_cast(unsigned short, b) << 16);
  }
  u32x4 val = {d[0], d[1], d[2], (u32)(4 + E)};
  hdt[(4 + E) * SLAB + r] = val;
}

__device__ __forceinline__ void store_h_agent(f16* p, float v) {
  f16 h = (f16)v;
  __hip_atomic_store((unsigned short*)p, __builtin_bit_cast(unsigned short, h),
                     __ATOMIC_RELAXED, __HIP_MEMORY_SCOPE_AGENT);
}

#define SWZ(ROW, BOFF) (((ROW) << 10) + ((BOFF) ^ ((((ROW) & 7)) << 4)))

#define VMCNT0() do {                                                             \
    asm volatile("s_waitcnt vmcnt(0)" ::: "memory");                              \
    __builtin_amdgcn_sched_barrier(0);                                            \
  } while (0)

#define RAWBAR() do {                                                             \
    asm volatile("s_waitcnt lgkmcnt(0)" ::: "memory");                            \
    __builtin_amdgcn_sched_barrier(0);                                            \
    __builtin_amdgcn_s_barrier();                                                 \
    __builtin_amdgcn_sched_barrier(0);                                            \
  } while (0)

#define WAVE_ORDER() do {                                                          \
    asm volatile("s_waitcnt vmcnt(16)" ::: "memory");                              \
    __builtin_amdgcn_sched_barrier(0);                                             \
  } while (0)

// Encoder group barrier (128 blocks sharing emt) — unchanged from R10.
#define END_STEP_ENC(TARGET) do {                                                  \
    __builtin_amdgcn_s_barrier();                                                  \
    asm volatile("" ::: "memory");                                                 \
    if (tid == 0)                                                                  \
      __hip_atomic_store(&bar[bflag], (TARGET), __ATOMIC_RELAXED,                  \
                         __HIP_MEMORY_SCOPE_AGENT);                                \
    if (wid == 0) {                                                                \
      for (;;) {                                                                   \
        int a0 = __hip_atomic_load(&bar[pe0], __ATOMIC_RELAXED,                    \
                                   __HIP_MEMORY_SCOPE_AGENT);                      \
        int a1 = __hip_atomic_load(&bar[pe1], __ATOMIC_RELAXED,                    \
                                   __HIP_MEMORY_SCOPE_AGENT);                      \
        if (a0 >= (TARGET) && a1 >= (TARGET)) break;                               \
        __builtin_amdgcn_s_sleep(1);                                               \
      }                                                                            \
    }                                                                              \
    __builtin_amdgcn_s_barrier();                                                  \
    asm volatile("" ::: "memory");                                                 \
    __builtin_amdgcn_sched_barrier(0);                                             \
  } while (0)

// Encoder body (R10 structure) + one-time tagged state0 emission at v==1023.
#define ENC_BODY(DD, P, TARGET) do {                                               \
    const int v = (DD) - eslot;                                                    \
    if (v >= 0 && v < 1024) {                                                      \
      const int L = v & 3, t = v >> 2;                                             \
      const f16* inp = (eslot == 0) ? (xt + (long)t * HSz)                         \
                                    : (h_enc + ((P)*4 + (eslot - 1)) * HSz);       \
      const f16* hin = h_enc + ((P)*4 + eslot) * HSz;                              \
      f16* hout = h_enc + ((1 - (P))*4 + eslot) * HSz;                             \
      {                                                                            \
        const f16* c0p = inp + emt * 16384;                                        \
        const f16* c1p = hin + emt * 16384;                                        \
        f16x8 tr[8];                                                               \
        _Pragma("unroll")                                                          \
        for (int k2 = 0; k2 < 4; ++k2) {                                           \
          const int s2 = tid + k2 * 512, row = s2 >> 6, c16 = s2 & 63;             \
          tr[k2]     = ldg_cohere(c0p + row * 512 + c16 * 8);                      \
          tr[k2 + 4] = ldg_cohere(c1p + row * 512 + c16 * 8);                      \
        }                                                                          \
        VMCNT0();                                                                  \
        _Pragma("unroll")                                                          \
        for (int k2 = 0; k2 < 4; ++k2) {                                           \
          const int s2 = tid + k2 * 512, row = s2 >> 6, c16 = s2 & 63;             \
          *(f16x8*)(AsBuf + SWZ(row, c16 * 16)) = tr[k2];                          \
          *(f16x8*)(AsBuf + 32768 + SWZ(row, c16 * 16)) = tr[k2 + 4];              \
        }                                                                          \
      }                                                                            \
      RAWBAR();                                                                    \
      f32x4 acc0 = 0.f, acc1 = 0.f;                                                \
      _Pragma("unroll")                                                            \
      for (int kk = 0; kk < 16; ++kk) {                                            \
        f16x8 a0 = *(const f16x8*)(AsBuf + kh * 32768 +                            \
                                   SWZ(col, kk * 64 + kg * 16));                   \
        f16x8 a1 = *(const f16x8*)(AsBuf + kh * 32768 +                            \
                                   SWZ(col + 16, kk * 64 + kg * 16));              \
        acc0 = __builtin_amdgcn_mfma_f32_16x16x32_f16(a0, B[kk], acc0, 0,0,0);     \
        acc1 = __builtin_amdgcn_mfma_f32_16x16x32_f16(a1, B[kk], acc1, 0,0,0);     \
      }                                                                            \
      _Pragma("unroll")                                                            \
      for (int r = 0; r < 4; ++r) {                                                \
        zredE[wid][kg*4 + r][col] = acc0[r];                                       \
        zredE[wid][16 + kg*4 + r][col] = acc1[r];                                  \
      }                                                                            \
      RAWBAR();                                                                    \
      const bool s0f = (v == 1023) && (eslot == 3);                                \
      {                                                                            \
        const int row = tid >> 4, ci = tid & 15, n = n0 + ci;                      \
        const float* bl = bias_enc_lds + L * 64 + ci;                              \
        float zf = bl[0]  + zredE[0][row][ci] + zredE[4][row][ci];                 \
        float zi = bl[16] + zredE[1][row][ci] + zredE[5][row][ci];                 \
        float zg = bl[32] + zredE[2][row][ci] + zredE[6][row][ci];                 \
        float zo = bl[48] + zredE[3][row][ci] + zredE[7][row][ci];                 \
        float f_ = sigmoidf_(zf), i_ = sigmoidf_(zi);                              \
        float g_ = tanhf_(zg),   o_ = sigmoidf_(zo);                               \
        const int grow = emt * 32 + row;                                           \
        float cin = (v == 0) ? enc_c0[(long)eslot * HSz + grow * SH + n] : ce;     \
        float cc = f_ * cin + i_ * g_;                                             \
        ce = cc;                                                                   \
        float hv = o_ * tanhf_(cc);                                                \
        store_h_agent(hout + grow * SH + n, hv);                                   \
        if (s0f) pb16[row * 16 + ci] = (f16)hv;                                    \
      }                                                                            \
      if (s0f) {                                                                   \
        RAWBAR();                                                                  \
        if (tid < 96) {                                                            \
          int u = tid % 3, rowp = tid / 3;                                         \
          const char* pbc = (const char*)pb16 + rowp * 32;                         \
          u32 d0, d1, d2;                                                          \
          if (u == 0) { u32x2 t2 = *(const u32x2*)(pbc);                           \
                        d0 = t2.x; d1 = t2.y; d2 = *(const u32*)(pbc + 8); }       \
          else if (u == 1) { d0 = *(const u32*)(pbc + 12);                         \
                             u32x2 t2 = *(const u32x2*)(pbc + 16);                 \
                             d1 = t2.x; d2 = t2.y; }                               \
          else { u32x2 t2 = *(const u32x2*)(pbc + 24);                             \
                 d0 = t2.x; d1 = t2.y; d2 = 0; }                                   \
          u32x4 val = {d0, d1, d2, 7u};                                            \
          stg_tag(s0t + (emt * 32 + rowp) * 96 + nt * 3 + u, val);                 \
        }                                                                          \
      }                                                                            \
      const f16* wn = (v + 1 < 1024)                                               \
          ? wt_enc + ((long)(((v + 1) & 3) * 4 + eslot) << 21) + wslice            \
          : wt_enc + wslice;                                                       \
      asm volatile("" ::: "memory");                                               \
      _Pragma("unroll")                                                            \
      for (int kk = 0; kk < 16; ++kk) B[kk] = *(const f16x8*)(wn + kk * 512);      \
      WAVE_ORDER();                                                                \
    }                                                                              \
    END_STEP_ENC(TARGET);                                                          \
  } while (0)

__global__ __launch_bounds__(512, 2) void lstm_persist(
    const f16* __restrict__ xt,
    const f16* __restrict__ wt_enc, const f16* __restrict__ wt_dec,
    const float* __restrict__ enc_b, const float* __restrict__ dec_b,
    const float* __restrict__ enc_c0, const float* __restrict__ dec_c0,
    f16* __restrict__ h_enc, u32x4* __restrict__ hdt, u32x4* __restrict__ s0t,
    f16* __restrict__ ys, int* __restrict__ bar) {
  const int tid = threadIdx.x;
  const int lane = tid & 63;
  const int wid = tid >> 6;
  const int g = wid & 3;      // encoder: gate; decoder: K-slice-in-half
  const int kh = wid >> 2;    // K-half (enc & dec)
  const int col = lane & 15;
  const int kg = lane >> 4;
  const int idx = blockIdx.x;
  const int nt = idx & 31;
  const int n0 = nt << 4;
  const int eslot = idx >> 6;
  const int emt = (idx >> 5) & 1;
  const int dmt = idx >> 5;

  const int bflag = idx * 32;
  const int pe0 = ((((lane) >> 5) << 6) | (emt << 5) | (lane & 31)) * 32;
  const int pe1 = (((((lane + 64)) >> 5) << 6) | (emt << 5) | ((lane + 64) & 31)) * 32;

  __shared__ __align__(16) char AsBuf[65536];
  __shared__ float zredE[8][32][17];
  __shared__ float zredD[8][4][8][17];
  __shared__ float bias_enc_lds[256];
  __shared__ float bias_dec_lds[1024];
  __shared__ __align__(16) f16 pb16[512];

  const long wslice = ((long)(nt * 4 + g) * 2 + kh) * 8192 + lane * 8;
  const int HSz = BS * SH;

  for (int i = tid; i < 256; i += 512) {
    int L = i >> 6, gg = (i >> 4) & 3, ci = i & 15;
    bias_enc_lds[i] = enc_b[(L * 4 + eslot) * 2048 + gg * 512 + n0 + ci];
  }
  for (int i = tid; i < 1024; i += 512) {
    int cell = i >> 6, gg = (i >> 4) & 3, ci = i & 15;
    bias_dec_lds[i] = dec_b[cell * 2048 + gg * 512 + n0 + ci];
  }

  f16x8 B[16];
  {
    const f16* w = wt_enc + ((long)eslot << 21) + wslice;
#pragma unroll
    for (int kk = 0; kk < 16; ++kk) B[kk] = *(const f16x8*)(w + kk * 512);
  }
  __syncthreads();

  float ce = 0.f;
  float cd0 = 0.f, cd1 = 0.f, cd2 = 0.f, cd3 = 0.f;

  // -------- encoder: anti-diagonal wavefront (R10, barriered) --------
  for (int d = 0;; d += 2) {
    ENC_BODY(d, 0, d + 1);
    if (d == 1026) break;
    ENC_BODY(d + 1, 1, d + 2);
  }

  // -------- reload B for decoder cell 0 with 4-gate-per-wave slicing --------
#pragma unroll
  for (int g2 = 0; g2 < 4; ++g2)
#pragma unroll
    for (int kkl = 0; kkl < 4; ++kkl)
      B[g2 * 4 + kkl] = *(const f16x8*)(wt_dec +
          ((long)(nt * 4 + g2) * 2 + kh) * 8192 + (g * 4 + kkl) * 512 + lane * 8);

  // -------- decoder: pure dataflow, tag-fused handoff, no global barriers ----
  for (int s = 0; s < 4096; ++s) {
    const int vv = s >> 2, E = s & 3, par = vv & 1, L = vv & 3;
    const u32 T = 8u + (u32)s;
    const u32x4* inpT;
    if (E > 0) inpT = hdt + (par * 4 + E - 1) * SLAB;
    else if (vv > 0) inpT = hdt + ((par ^ 1) * 4 + 3) * SLAB;
    else inpT = s0t;
    const u32x4* hinT = hdt + ((par ^ 1) * 4 + E) * SLAB;

    // ---- poll + stage: 3 tagged units per thread ----
    {
      const int q1 = tid + 512;
      const int c1 = (q1 >= 768);
      const int l0 = tid, l1 = q1 - (c1 ? 768 : 0), l2 = tid + 256;
      const u32x4* a0 = inpT + dmt * 768 + l0;
      const u32x4* a1 = (c1 ? hinT : inpT) + dmt * 768 + l1;
      const u32x4* a2 = hinT + dmt * 768 + l2;
      const u32 e0 = T - 1, e1 = c1 ? T - 4 : T - 1, e2 = T - 4;
      u32x4 r0, r1, r2;
      for (;;) {
        r0 = ldg_tag(a0); r1 = ldg_tag(a1); r2 = ldg_tag(a2);
        VMCNT0();
        if (r0.w == e0 && r1.w == e1 && r2.w == e2) break;
        __builtin_amdgcn_s_sleep(2);
      }
      // unpack
      const u32x4 rr[3] = {r0, r1, r2};
      const int ll[3] = {l0, l1, l2};
      const int cc3[3] = {0, c1, 1};
#pragma unroll
      for (int j = 0; j < 3; ++j) {
        int row = ll[j] / 96;
        int rem = ll[j] - row * 96;
        int unt = rem / 3;
        int u = rem - unt * 3;
        char* A = AsBuf + cc3[j] * 8192 + SWZ(row, unt * 32);
        char* B2 = AsBuf + cc3[j] * 8192 + SWZ(row, unt * 32 + 16);
        u32x4 r = rr[j];
        if (u == 0) { u32x2 t2 = {r.x, r.y}; *(u32x2*)A = t2; *(u32*)(A + 8) = r.z; }
        else if (u == 1) { *(u32*)(A + 12) = r.x; u32x2 t2 = {r.y, r.z}; *(u32x2*)B2 = t2; }
        else { u32x2 t2 = {r.x, r.y}; *(u32x2*)(B2 + 8) = t2; }
      }
    }
    RAWBAR();

    // ---- MFMA: wave (kh, g=K-sub-slice): 4 gates x 4 kkl, A reused x4 ----
    f16x8 a_[4];
#pragma unroll
    for (int kkl = 0; kkl < 4; ++kkl)
      a_[kkl] = *(const f16x8*)(AsBuf + kh * 8192 +
                                SWZ(col & 7, g * 256 + kkl * 64 + kg * 16));
    f32x4 accg0 = 0.f, accg1 = 0.f, accg2 = 0.f, accg3 = 0.f;
#pragma unroll
    for (int kkl = 0; kkl < 4; ++kkl) {
      accg0 = __builtin_amdgcn_mfma_f32_16x16x32_f16(a_[kkl], B[0 * 4 + kkl], accg0, 0,0,0);
      accg1 = __builtin_amdgcn_mfma_f32_16x16x32_f16(a_[kkl], B[1 * 4 + kkl], accg1, 0,0,0);
      accg2 = __builtin_amdgcn_mfma_f32_16x16x32_f16(a_[kkl], B[2 * 4 + kkl], accg2, 0,0,0);
      accg3 = __builtin_amdgcn_mfma_f32_16x16x32_f16(a_[kkl], B[3 * 4 + kkl], accg3, 0,0,0);
    }
    if (kg < 2) {
#pragma unroll
      for (int r = 0; r < 4; ++r) {
        zredD[wid][0][kg * 4 + r][col] = accg0[r];
        zredD[wid][1][kg * 4 + r][col] = accg1[r];
        zredD[wid][2][kg * 4 + r][col] = accg2[r];
        zredD[wid][3][kg * 4 + r][col] = accg3[r];
      }
    }
    // weight prefetch for next cell (B dead after MFMA)
    if (s + 1 < 4096) {
      const int s2 = s + 1;
      const long cell2 = (long)((((s2 >> 2) & 3) * 4) + (s2 & 3));
      const f16* wb = wt_dec + (cell2 << 21);
      asm volatile("" ::: "memory");
#pragma unroll
      for (int g2 = 0; g2 < 4; ++g2)
#pragma unroll
        for (int kkl = 0; kkl < 4; ++kkl)
          B[g2 * 4 + kkl] = *(const f16x8*)(wb +
              ((long)(nt * 4 + g2) * 2 + kh) * 8192 + (g * 4 + kkl) * 512 + lane * 8);
    }
    RAWBAR();

    // ---- gate phase (tid<128): z sums, gates, c, h ----
    if (tid < 128) {
      const int row = tid >> 4, ci = tid & 15, n = n0 + ci;
      const float* bl = bias_dec_lds + (L * 4 + E) * 64 + ci;
      float zf = bl[0], zi = bl[16], zg = bl[32], zo = bl[48];
#pragma unroll
      for (int w = 0; w < 8; ++w) {
        zf += zredD[w][0][row][ci];
        zi += zredD[w][1][row][ci];
        zg += zredD[w][2][row][ci];
        zo += zredD[w][3][row][ci];
      }
      float f_ = sigmoidf_(zf), i_ = sigmoidf_(zi);
      float g_ = tanhf_(zg),   o_ = sigmoidf_(zo);
      float cin;
      if (vv == 0) cin = dec_c0[(long)E * HSz + (dmt * 8 + row) * SH + n];
      else cin = (E == 0) ? cd0 : (E == 1) ? cd1 : (E == 2) ? cd2 : cd3;
      float cc = f_ * cin + i_ * g_;
      if (E == 0) cd0 = cc; else if (E == 1) cd1 = cc;
      else if (E == 2) cd2 = cc; else cd3 = cc;
      float hv = o_ * tanhf_(cc);
      pb16[row * 16 + ci] = (f16)hv;
      if (E == 3) ys[((long)(dmt * 8 + row) * 1024 + vv) * SH + n] = (f16)hv;
    }
    RAWBAR();

    // ---- tagged h store (tid<24): pack 8 rows x 16 cols into 24 units ----
    if (tid < 24) {
      const int u = tid % 3, rowp = tid / 3;
      const char* pbc = (const char*)pb16 + rowp * 32;
      u32 d0, d1, d2;
      if (u == 0) { u32x2 t2 = *(const u32x2*)(pbc);
                    d0 = t2.x; d1 = t2.y; d2 = *(const u32*)(pbc + 8); }
      else if (u == 1) { d0 = *(const u32*)(pbc + 12);
                         u32x2 t2 = *(const u32x2*)(pbc + 16);
                         d1 = t2.x; d2 = t2.y; }
      else { u32x2 t2 = *(const u32x2*)(pbc + 24);
             d0 = t2.x; d1 = t2.y; d2 = 0; }
      u32x4 val = {d0, d1, d2, T};
      stg_tag(hdt + (par * 4 + E) * SLAB + (dmt * 8 + rowp) * 96 + nt * 3 + u, val);
    }
  }
}

// out[m][n] = sigmoid( ys[m][:] @ fint[n][:] + fin_b[n] )
__global__ __launch_bounds__(256) void final_gemm(const f16* __restrict__ ys,
                                                  const f16* __restrict__ fint,
                                                  const float* __restrict__ finb,
                                                  float* __restrict__ out) {
  const int lane = threadIdx.x & 63;
  const int w = threadIdx.x >> 6;
  const int col = lane & 15;
  const int kg = lane >> 4;
  const long m0 = (long)blockIdx.y * 64;
  const int n0 = (blockIdx.x * 4 + w) * 16;

  f32x4 acc[4];
#pragma unroll
  for (int mi = 0; mi < 4; ++mi) acc[mi] = 0.f;

#pragma unroll 2
  for (int kk = 0; kk < 16; ++kk) {
    f16x8 b = *(const f16x8*)(fint + (long)(n0 + col) * 512 + kk * 32 + kg * 8);
#pragma unroll
    for (int mi = 0; mi < 4; ++mi) {
      f16x8 a = *(const f16x8*)(ys + (m0 + mi * 16 + col) * 512 + kk * 32 + kg * 8);
      acc[mi] = __builtin_amdgcn_mfma_f32_16x16x32_f16(a, b, acc[mi], 0, 0, 0);
    }
  }
  const int n = n0 + col;
  const float bn = finb[n];
#pragma unroll
  for (int mi = 0; mi < 4; ++mi)
#pragma unroll
    for (int r = 0; r < 4; ++r)
      out[(m0 + mi * 16 + kg * 4 + r) * 512 + n] = sigmoidf_(acc[mi][r] + bn);
}

extern "C" void kernel_launch(void* const* d_in, const int* in_sizes, int n_in,
                              void* d_out, int out_size, void* d_ws, size_t ws_size,
                              hipStream_t stream) {
  const float* x      = (const float*)d_in[0];
  const float* enc_W  = (const float*)d_in[2];
  const float* enc_V  = (const float*)d_in[3];
  const float* enc_b  = (const float*)d_in[4];
  const float* enc_h0 = (const float*)d_in[5];
  const float* enc_c0 = (const float*)d_in[6];
  const float* dec_W  = (const float*)d_in[7];
  const float* dec_V  = (const float*)d_in[8];
  const float* dec_b  = (const float*)d_in[9];
  const float* dec_h0 = (const float*)d_in[10];
  const float* dec_c0 = (const float*)d_in[11];
  const float* fin_W  = (const float*)d_in[12];
  const float* fin_b  = (const float*)d_in[13];
  float* out = (float*)d_out;

  // workspace layout
  f16* wt_enc = (f16*)d_ws;                                   // 16*2048*1024
  f16* wt_dec = wt_enc + (long)16 * 2048 * 1024;              // 16*2048*1024
  f16* xt     = wt_dec + (long)16 * 2048 * 1024;              // 256*64*512
  f16* fint   = xt + (long)SL * BS * SI;                      // 512*512
  f16* ys     = fint + (long)SH * SI;                         // 64*1024*512
  f16* h_enc  = ys + (long)BS * (FL * 4) * SH;                // 2*4*64*512
  f16* h_unused = h_enc + (long)2 * 4 * BS * SH;              // reserved
  float* c_unused = (float*)(h_unused + (long)2 * 4 * BS * SH);
  int* bar = (int*)(c_unused + (long)8 * BS * SH);            // 256 flags x 128B
  u32x4* hdt = (u32x4*)((char*)bar + 65536);                  // 8 slabs x 6144 units
  u32x4* s0t = hdt + 8 * SLAB;                                // 6144 units

  hipMemsetAsync(bar, 0, 65536, stream);
  hipMemsetAsync(hdt, 0, (size_t)(8 * SLAB + SLAB) * 16, stream);

  conv_w<<<131072, 256, 0, stream>>>(enc_W, enc_V, wt_enc);
  conv_w<<<131072, 256, 0, stream>>>(dec_W, dec_V, wt_dec);
  conv_x<<<32768, 256, 0, stream>>>(x, xt);
  conv_fin<<<1024, 256, 0, stream>>>(fin_W, fint);
  init_state<<<512, 256, 0, stream>>>(enc_h0, h_enc);
  init_dec_tags<<<96, 256, 0, stream>>>(dec_h0, hdt);

  lstm_persist<<<NBLK, 512, 0, stream>>>(xt, wt_enc, wt_dec, enc_b, dec_b,
                                         enc_c0, dec_c0, h_enc, hdt, s0t, ys, bar);

  dim3 fg(8, 1024);
  final_gemm<<<fg, 256, 0, stream>>>(ys, fint, fin_b, out);
}